// Round 9
// baseline (147.947 us; speedup 1.0000x reference)
//
#include <hip/hip_runtime.h>

// Morphological max-plus dilation, 'same' padding, K=5.
// out[b,o,y,x] = max_{c,i,j} f[b,c,y+i-2,x+j-2] + h[o,c,i,j]
// f(8,32,96,96) fp32, h(32,32,5,5) fp32, out(8,32,96,96) fp32.
//
// R9 = R8 with h moved from LDS to SGPRs. R8's inner loop serialized on
// per-(i,j) ds_read_b64 + lgkmcnt (VGPR=32 shows the compiler never batched
// them); all resident waves stalled on the same LDS latency. h indices are
// wave-uniform -> pre-pack h2 pairs into d_ws and read with uniform indices:
// compiler emits batched s_load into SGPRs (h table = 64 KB, K$-resident).
// Inner ij-loop is then pure VALU: v_pk_*(v_window, s_h), no ds, no lgkm.
//  - packed-fp16 math (absmax 0.031 << 0.1 threshold)
//  - f pre-padded in d_ws as DUPLICATED half2 (v,v) dwords with NEG halo
//  - grid/tiling identical to R8: 1536 blocks x 384 thr, CS=4 c-split

#define B_ 8
#define C_ 32
#define O_ 32
#define H_ 96
#define W_ 96
#define K_ 5
#define KK_ (K_ * K_)      // 25

#define TX_ 24             // threads along x; 24*4 = 96 = W
#define RT_ 4              // row-threads per group (4 output rows per block)
#define CS_ 4              // in-block c-split groups
#define TY_ (RT_ * CS_)    // 16
#define NT_ (TX_ * TY_)    // 384 threads = 6 waves
#define XR_ 4              // x outputs per thread
#define OP_ 2              // half2 o-pairs per thread
#define OB_ (OP_ * 2)      // 4 o-channels per block
#define CG_ (C_ / CS_)     // 8 c's per group

// padded f: [b][c][PH][PW] dwords; row = y+2 (0..99), col = x+2 (pad to 104)
#define PH_ 100
#define PW_ 104
#define PLSZ_ (PH_ * PW_)
#define FPAD_BYTES ((size_t)B_ * C_ * PLSZ_ * 4)   // 10,649,600

// packed h: [q][c][32] dwords, q = o/2 (16 rows), entry dword = h2(h[2q],h[2q+1])
// stride 32 dwords (128 B) for aligned s_load batching. 16*32*32*4 = 64 KB.
#define HQ_ (O_ / 2)
#define HSTR_ 32
#define HPACK_DW (HQ_ * C_ * HSTR_)

#define NEGF (-30000.0f)

typedef _Float16 h2 __attribute__((ext_vector_type(2)));

static __device__ __forceinline__ h2 h2b(unsigned u) {
    return __builtin_bit_cast(h2, u);
}
static __device__ __forceinline__ unsigned bh2(h2 v) {
    return __builtin_bit_cast(unsigned, v);
}

// ---------------- pre-pad: f fp32 -> duplicated half2 with NEG halo ----------
__global__ __launch_bounds__(256)
void prepad_kernel(const float* __restrict__ f, unsigned* __restrict__ fpad) {
    const int idx = blockIdx.x * 256 + threadIdx.x;
    const int c = blockIdx.y;
    const int b = blockIdx.z;
    if (idx >= PLSZ_) return;
    const int row = idx / PW_;
    const int col = idx - row * PW_;
    const int y = row - 2;
    const int x = col - 2;
    float v = NEGF;
    if ((unsigned)y < H_ && (unsigned)x < W_)
        v = f[((size_t)(b * C_ + c) * H_ + y) * W_ + x];
    _Float16 hv = (_Float16)v;
    h2 d; d.x = hv; d.y = hv;
    fpad[(size_t)(b * C_ + c) * PLSZ_ + idx] = bh2(d);
}

// ---------------- pack h: h2(h[2q][c][ij], h[2q+1][c][ij]) -------------------
__global__ __launch_bounds__(256)
void hpack_kernel(const float* __restrict__ h, unsigned* __restrict__ hpack) {
    const int idx = blockIdx.x * 256 + threadIdx.x;
    if (idx >= HQ_ * C_ * KK_) return;
    const int q  = idx / (C_ * KK_);
    const int r  = idx - q * (C_ * KK_);
    const int c  = r / KK_;
    const int ij = r - c * KK_;
    float a0 = h[((size_t)(2 * q)     * C_ + c) * KK_ + ij];
    float a1 = h[((size_t)(2 * q + 1) * C_ + c) * KK_ + ij];
    h2 p; p.x = (_Float16)a0; p.y = (_Float16)a1;
    hpack[((size_t)q * C_ + c) * HSTR_ + ij] = bh2(p);
}

// ---------------- main kernel ------------------------------------------------
template <bool PADDED>
__global__ __launch_bounds__(NT_)
void dilate_main(const unsigned* __restrict__ fpad,
                 const unsigned* __restrict__ hpack,
                 const float* __restrict__ f,
                 const float* __restrict__ h, float* __restrict__ out) {
    const int tx  = threadIdx.x;           // 0..23
    const int ty  = threadIdx.y;           // 0..15
    const int ry  = ty & (RT_ - 1);        // row-thread 0..3
    const int g   = ty >> 2;               // c-split group 0..3

    const int ytile = blockIdx.x;          // 0..23
    const int og    = blockIdx.y;          // 0..7
    const int b     = blockIdx.z;          // 0..7
    const int y0 = ytile * RT_;            // 4 rows per block
    const int o0 = og * OB_;
    const int q0 = og * OP_;               // hpack row for op=0
    const int x0 = XR_ * tx;               // 0..92
    const int yb = y0 + ry;                // this thread's output row

    __shared__ unsigned comb[CS_ - 1][OP_ * XR_][RT_ * TX_];  // 9216 B

    h2 acc[OP_][XR_];
    {
        h2 neg; neg.x = (_Float16)NEGF; neg.y = (_Float16)NEGF;
#pragma unroll
        for (int op = 0; op < OP_; ++op)
#pragma unroll
            for (int xx = 0; xx < XR_; ++xx) acc[op][xx] = neg;
    }

    const int c0 = g * CG_;
    for (int cc = 0; cc < CG_; ++cc) {
        const int c = c0 + cc;

        // ---- h for this c: wave-uniform indices -> scalar loads into SGPRs --
        unsigned hr0[KK_], hr1[KK_];
        if (PADDED) {
            const unsigned* hq = hpack + ((size_t)(q0 * C_ + c)) * HSTR_;
#pragma unroll
            for (int ij = 0; ij < KK_; ++ij) {
                hr0[ij] = hq[ij];
                hr1[ij] = hq[C_ * HSTR_ + ij];   // row q0+1
            }
        } else {
            // fallback: uniform fp32 loads + inline cvt (also scalarizes)
#pragma unroll
            for (int ij = 0; ij < KK_; ++ij) {
                float a0 = h[((size_t)o0       * C_ + c) * KK_ + ij];
                float a1 = h[((size_t)(o0 + 1) * C_ + c) * KK_ + ij];
                float a2 = h[((size_t)(o0 + 2) * C_ + c) * KK_ + ij];
                float a3 = h[((size_t)(o0 + 3) * C_ + c) * KK_ + ij];
                h2 p0; p0.x = (_Float16)a0; p0.y = (_Float16)a1;
                h2 p1; p1.x = (_Float16)a2; p1.y = (_Float16)a3;
                hr0[ij] = bh2(p0);
                hr1[ij] = bh2(p1);
            }
        }

        // ---- window: 5 rows x 8 dwords ----
        h2 a[K_][8];
        if (PADDED) {
            const unsigned* p =
                fpad + (size_t)(b * C_ + c) * PLSZ_ + yb * PW_ + x0;
#pragma unroll
            for (int i = 0; i < K_; ++i) {
                const uint4* q = (const uint4*)(p + i * PW_);
                uint4 w0 = q[0];
                uint4 w1 = q[1];
                a[i][0] = h2b(w0.x); a[i][1] = h2b(w0.y);
                a[i][2] = h2b(w0.z); a[i][3] = h2b(w0.w);
                a[i][4] = h2b(w1.x); a[i][5] = h2b(w1.y);
                a[i][6] = h2b(w1.z); a[i][7] = h2b(w1.w);
            }
        } else {
            const float* fc = f + (size_t)(b * C_ + c) * (H_ * W_);
#pragma unroll
            for (int i = 0; i < K_; ++i) {
                const int yy = yb + i - 2;
                const bool yok = (unsigned)yy < H_;
                const float* frow = fc + (size_t)(yok ? yy : 0) * W_;
#pragma unroll
                for (int q = 0; q < 8; ++q) {
                    int xc = x0 - 2 + q;
                    bool ok = yok && ((unsigned)xc < W_);
                    float v = frow[ok ? xc : 0];
                    v = ok ? v : NEGF;
                    _Float16 hv = (_Float16)v;
                    h2 d; d.x = hv; d.y = hv;
                    a[i][q] = d;
                }
            }
        }

        // ---- pure-VALU inner loop: v_pk_*(v_window, s_h) --------------------
#pragma unroll
        for (int i = 0; i < K_; ++i) {
#pragma unroll
            for (int j = 0; j < K_; ++j) {
                h2 h0 = h2b(hr0[i * K_ + j]);
                h2 h1 = h2b(hr1[i * K_ + j]);
#pragma unroll
                for (int xx = 0; xx < XR_; ++xx) {
                    h2 fv = a[i][xx + j];
                    acc[0][xx] = __builtin_elementwise_max(acc[0][xx], fv + h0);
                    acc[1][xx] = __builtin_elementwise_max(acc[1][xx], fv + h1);
                }
            }
        }
    }

    // ---- combine the four c-groups via LDS (lane-contiguous, conflict-free) -
    const int t96 = ry * TX_ + tx;   // 0..95 within group
    if (g > 0) {
#pragma unroll
        for (int op = 0; op < OP_; ++op)
#pragma unroll
            for (int xx = 0; xx < XR_; ++xx)
                comb[g - 1][op * XR_ + xx][t96] = bh2(acc[op][xx]);
    }
    __syncthreads();
    if (g == 0) {
#pragma unroll
        for (int op = 0; op < OP_; ++op)
#pragma unroll
            for (int xx = 0; xx < XR_; ++xx) {
                const int row = op * XR_ + xx;
                h2 v0 = h2b(comb[0][row][t96]);
                h2 v1 = h2b(comb[1][row][t96]);
                h2 v2 = h2b(comb[2][row][t96]);
                h2 m = __builtin_elementwise_max(v0, v1);
                m = __builtin_elementwise_max(m, v2);
                acc[op][xx] = __builtin_elementwise_max(acc[op][xx], m);
            }

        // epilogue: unpack to fp32, coalesced float4 per o-plane
        const int y = yb;
#pragma unroll
        for (int op = 0; op < OP_; ++op) {
            const int o = o0 + 2 * op;
            float4 lo = make_float4((float)acc[op][0].x, (float)acc[op][1].x,
                                    (float)acc[op][2].x, (float)acc[op][3].x);
            float4 hi = make_float4((float)acc[op][0].y, (float)acc[op][1].y,
                                    (float)acc[op][2].y, (float)acc[op][3].y);
            *(float4*)&out[(((size_t)b * O_ + o)     * H_ + y) * W_ + x0] = lo;
            *(float4*)&out[(((size_t)b * O_ + o + 1) * H_ + y) * W_ + x0] = hi;
        }
    }
}

extern "C" void kernel_launch(void* const* d_in, const int* in_sizes, int n_in,
                              void* d_out, int out_size, void* d_ws, size_t ws_size,
                              hipStream_t stream) {
    const float* f = (const float*)d_in[0];
    const float* h = (const float*)d_in[1];
    float* out = (float*)d_out;

    dim3 mgrid(H_ / RT_, O_ / OB_, B_);   // (24, 8, 8) = 1536 blocks
    dim3 mblock(TX_, TY_);                // 384 threads = 6 waves

    const size_t need = FPAD_BYTES + (size_t)HPACK_DW * 4;   // ~10.7 MB + 64 KB
    if (ws_size >= need) {
        unsigned* fpad  = (unsigned*)d_ws;
        unsigned* hpack = (unsigned*)((char*)d_ws + FPAD_BYTES);
        dim3 pgrid((PLSZ_ + 255) / 256, C_, B_);
        hipLaunchKernelGGL(prepad_kernel, pgrid, dim3(256), 0, stream, f, fpad);
        hipLaunchKernelGGL(hpack_kernel, dim3((HQ_ * C_ * KK_ + 255) / 256),
                           dim3(256), 0, stream, h, hpack);
        hipLaunchKernelGGL((dilate_main<true>), mgrid, mblock, 0, stream,
                           fpad, hpack, f, h, out);
    } else {
        hipLaunchKernelGGL((dilate_main<false>), mgrid, mblock, 0, stream,
                           (const unsigned*)nullptr, (const unsigned*)nullptr,
                           f, h, out);
    }
}